// Round 8
// baseline (151.474 us; speedup 1.0000x reference)
//
#include <hip/hip_runtime.h>
#include <hip/hip_bf16.h>

typedef _Float16 f16;
typedef _Float16 f16x8 __attribute__((ext_vector_type(8)));
typedef float f32x4 __attribute__((ext_vector_type(4)));

constexpr int TS = 2048;   // time steps / params length
constexpr int BB = 4096;   // batch rows

struct ToepShared { char Xs[16384]; char Ws[8192]; };

// h-block shared state, lane-consecutive / broadcast accesses
struct __align__(16) HShared {
  float rq[2048];          // rq[z] = p[2047-z]
  float h[2048];           // linear impulse response
  float histp_store[1280]; // histp = store+256; zero prefix absorbs r>i reads
};

// ---------------------------------------------------------------------------
// toep body: triangular Toeplitz x dense GEMM via mfma_f32_16x16x32_f16.
//   REV=true  (stage A): u[b,m] = bias + sum_{k>=m} prv[k-m] * x[b,k] -> f16
//   REV=false (stage C): y[b,m] =        sum_{k<=m} h[m-k]  * u[b,k] -> f32
// Block: 128 rows x 64 cols, 4 waves (2x2), BK=64, column pairing (px,31-px).
// ---------------------------------------------------------------------------
template <bool REV>
__device__ void toep_body(ToepShared& lds, int w, const f16* __restrict__ Xg,
                          const char* __restrict__ Wg,
                          const float* __restrict__ biasp, void* __restrict__ Yg) {
  char* Xs = lds.Xs;
  char* Ws = lds.Ws;
  const int tid = threadIdx.x;
  const int lane = tid & 63;
  const int wid = tid >> 6;
  const int wrow = (wid >> 1) * 64;
  const int wcol = (wid & 1) * 32;
  const int px = w & 15;
  const int b0 = (w >> 4) * 128;

  float binit = 0.0f;
  if (REV) binit = biasp[0];

  for (int phase = 0; phase < 2; ++phase) {
    const int mblk = phase ? (31 - px) : px;
    const int m0 = mblk * 64;
    const int k0b = REV ? m0 : 0;
    const int k0e = REV ? TS : (m0 + 64);

    f32x4 acc[4][2];
    #pragma unroll
    for (int i = 0; i < 4; ++i)
      #pragma unroll
      for (int j = 0; j < 2; ++j) acc[i][j] = {binit, binit, binit, binit};

    for (int k0 = k0b; k0 < k0e; k0 += 64) {
      __syncthreads();
      // stage X tile: 16 x 1KB, inverse-swizzled per-lane global source
      #pragma unroll
      for (int t2 = 0; t2 < 4; ++t2) {
        const int t = wid * 4 + t2;
        const int row = t * 8 + (lane >> 3);
        const char* src = (const char*)Xg + ((size_t)(b0 + row) * TS + k0) * 2
                          + (((lane & 7) * 16) ^ ((row & 7) << 4));
        __builtin_amdgcn_global_load_lds(
            (const __attribute__((address_space(1))) unsigned int*)src,
            (__attribute__((address_space(3))) unsigned int*)(Xs + t * 1024),
            16, 0, 0);
      }
      // stage W tile (pre-swizzled in global): 8 x 1KB
      const int dlt = (REV ? (k0 - m0) : (m0 - k0)) >> 6;
      const char* wsrc = Wg + (size_t)dlt * 8192;
      #pragma unroll
      for (int p = 0; p < 2; ++p) {
        const int t = wid * 2 + p;
        __builtin_amdgcn_global_load_lds(
            (const __attribute__((address_space(1))) unsigned int*)(wsrc + t * 1024 + lane * 16),
            (__attribute__((address_space(3))) unsigned int*)(Ws + t * 1024),
            16, 0, 0);
      }
      __syncthreads();

      #pragma unroll
      for (int ks = 0; ks < 2; ++ks) {
        const int colb = ks * 64 + ((lane >> 4) * 16);
        f16x8 af[4], bf[2];
        #pragma unroll
        for (int i = 0; i < 4; ++i) {
          const int row = wrow + i * 16 + (lane & 15);
          af[i] = *(const f16x8*)(Xs + row * 128 + (colb ^ ((row & 7) << 4)));
        }
        #pragma unroll
        for (int j = 0; j < 2; ++j) {
          const int n = wcol + j * 16 + (lane & 15);
          bf[j] = *(const f16x8*)(Ws + n * 128 + (colb ^ ((n & 7) << 4)));
        }
        #pragma unroll
        for (int i = 0; i < 4; ++i)
          #pragma unroll
          for (int j = 0; j < 2; ++j)
            acc[i][j] = __builtin_amdgcn_mfma_f32_16x16x32_f16(
                af[i], bf[j], acc[i][j], 0, 0, 0);
      }
    }

    // epilogue: C/D layout col=lane&15, row=(lane>>4)*4+r
    #pragma unroll
    for (int i = 0; i < 4; ++i) {
      #pragma unroll
      for (int j = 0; j < 2; ++j) {
        #pragma unroll
        for (int r = 0; r < 4; ++r) {
          const int row = b0 + wrow + i * 16 + (lane >> 4) * 4 + r;
          const int col = m0 + wcol + j * 16 + (lane & 15);
          if (REV)
            ((f16*)Yg)[(size_t)row * TS + col] = (f16)acc[i][j][r];
          else
            ((float*)Yg)[(size_t)row * TS + col] = acc[i][j][r];
        }
      }
    }
  }
}

// ---------------------------------------------------------------------------
// h-block (256 threads): impulse response by 6 doubling phases.
//   doubling n -> 2n:  hist[i] = sum_{m<n} h[m] p[n-1+i-m]      (i in [0,n))
//                      h[n+i]  = sum_{r<=i} h[r] hist[i-r]
// Lane owns 8 CONSECUTIVE outputs i0=8*tid. Inner loop processes 32 m-terms
// per iteration with ALL 18 LDS loads batched up front (10 window chunks +
// 8 uniform h chunks), then 256 FMAs -> load latency hidden by issue, loop
// is FMA-issue-bound instead of latency-serialized.
// ---------------------------------------------------------------------------
__device__ void h_block_body(HShared& S, const float* __restrict__ params,
                             char* __restrict__ WgC) {
  float* rq = S.rq;
  float* h_s = S.h;
  float* histp = S.histp_store + 256;
  const int tid = threadIdx.x;  // 0..255
  const int lane = tid & 63;
  const int wave = tid >> 6;

  // rq[z] = p[2047-z]
  for (int c = tid; c < 512; c += 256) {
    f32x4 pv = *(const f32x4*)&params[2044 - 4 * c];
    f32x4 v = {pv[3], pv[2], pv[1], pv[0]};
    *(f32x4*)&rq[4 * c] = v;
  }
  // zero histp prefix
  for (int c = tid; c < 64; c += 256) {
    f32x4 z = {0.0f, 0.0f, 0.0f, 0.0f};
    *(f32x4*)&S.histp_store[4 * c] = z;
  }
  __syncthreads();

  // bootstrap h[0..31] in wave 0: h[m] = sum_{l<m} h[l] p[m-1-l]
  if (wave == 0) {
    float hv = (lane == 0) ? 1.0f : 0.0f;
    for (int m = 1; m < 32; ++m) {
      float partial = (lane < m) ? hv * rq[2048 - m + lane] : 0.0f;
      #pragma unroll
      for (int off = 32; off; off >>= 1) partial += __shfl_xor(partial, off);
      if (lane == m) hv = partial;
    }
    if (lane < 32) h_s[lane] = hv;
  }
  __syncthreads();

  const int i0 = 8 * tid;

  #pragma unroll 1
  for (int n = 32; n < 2048; n <<= 1) {
    // ---- phase H: hist[i0+j] = sum_m h[m] rq[2048-n-i0-j+m] ----
    if (i0 < n) {
      float a[8];
      #pragma unroll
      for (int j = 0; j < 8; ++j) a[j] = 0.0f;
      const int cb = (2048 - n - i0) >> 2;  // chunk of rq[base], +8 per mb
      const int MB = n >> 5;
      for (int mb = 0; mb < MB; ++mb) {
        f32x4 w[10], hh[8];
        #pragma unroll
        for (int q = 0; q < 10; ++q)
          w[q] = *(const f32x4*)&rq[4 * (cb + 8 * mb - 2 + q)];
        #pragma unroll
        for (int q = 0; q < 8; ++q)
          hh[q] = *(const f32x4*)&h_s[4 * (8 * mb + q)];  // uniform broadcast
        #pragma unroll
        for (int d = 0; d < 32; ++d) {
          const float hd = hh[d >> 2][d & 3];
          #pragma unroll
          for (int j = 0; j < 8; ++j) {
            const int z = 8 + d - j;  // w-flat = rq[base+32mb-8+z]
            a[j] += hd * w[z >> 2][z & 3];
          }
        }
      }
      f32x4 lo = {a[0], a[1], a[2], a[3]};
      f32x4 hi = {a[4], a[5], a[6], a[7]};
      *(f32x4*)&histp[i0] = lo;
      *(f32x4*)&histp[i0 + 4] = hi;
    }
    __syncthreads();

    // ---- phase S: h[n+i0+j] = sum_{r<=i0+j} h[r] histp[i0+j-r] ----
    if (i0 < n) {
      float a[8];
      #pragma unroll
      for (int j = 0; j < 8; ++j) a[j] = 0.0f;
      const int cs = i0 >> 2;
      const int MB2 = (i0 + 39) >> 5;  // covers r <= i0+7; zero prefix pads
      for (int rb = 0; rb < MB2; ++rb) {
        f32x4 w[10], hh[8];
        #pragma unroll
        for (int q = 0; q < 10; ++q)
          w[q] = *(const f32x4*)&histp[4 * (cs - 8 * rb - 8 + q)];
        #pragma unroll
        for (int q = 0; q < 8; ++q)
          hh[q] = *(const f32x4*)&h_s[4 * (8 * rb + q)];  // uniform broadcast
        #pragma unroll
        for (int d = 0; d < 32; ++d) {
          const float hd = hh[d >> 2][d & 3];
          #pragma unroll
          for (int j = 0; j < 8; ++j) {
            const int z = 32 + j - d;  // histp[i0-32rb-32+z]; prefix-safe
            a[j] += hd * w[z >> 2][z & 3];
          }
        }
      }
      f32x4 lo = {a[0], a[1], a[2], a[3]};
      f32x4 hi = {a[4], a[5], a[6], a[7]};
      *(f32x4*)&h_s[n + i0] = lo;
      *(f32x4*)&h_s[n + i0 + 4] = hi;
    }
    __syncthreads();
  }

  // ---- stage-C W tiles: W[k][n2] = h[dlt*64 + n2 - k], pre-swizzled ----
  const int kq = tid >> 6;       // 0..3
  const int n2 = tid & 63;       // 0..63
  for (int dlt = 0; dlt < 32; ++dlt) {
    char* tile = WgC + (size_t)dlt * 8192;
    #pragma unroll
    for (int part = 0; part < 2; ++part) {
      const int k8 = kq * 16 + part * 8;
      f16x8 v;
      #pragma unroll
      for (int ii = 0; ii < 8; ++ii) {
        const int dd = dlt * 64 + n2 - (k8 + ii);
        v[ii] = ((unsigned)dd < (unsigned)TS) ? (f16)h_s[dd] : (f16)0.0f;
      }
      *(f16x8*)(tile + n2 * 128 + ((2 * k8) ^ ((n2 & 7) << 4))) = v;
    }
  }
}

// ---------------------------------------------------------------------------
// Kernel 1: block 0 = h + stage-C W tiles; blocks 1..32 = stage-A W tiles;
// blocks 33..2080 = X fp32->f16 conversion (overlaps the h block).
// ---------------------------------------------------------------------------
__global__ __launch_bounds__(256, 1) void conv_prep(
    const float* __restrict__ X, f16* __restrict__ Xh,
    const float* __restrict__ params, char* __restrict__ Wg) {
  __shared__ HShared S;
  const int b = blockIdx.x;
  const int tid = threadIdx.x;

  if (b == 0) {  // ---- h computation + stage-C W tiles ----
    h_block_body(S, params, Wg + 32 * 8192);
    return;
  }
  if (b <= 32) {  // ---- stage-A W tiles: W[k][n] = p[2047-(dlt*64+k-n)] ----
    const int dlt = b - 1;
    char* tile = Wg + (size_t)dlt * 8192;
    const int n = tid >> 2, kq = tid & 3;
    #pragma unroll
    for (int part = 0; part < 2; ++part) {
      const int k8 = kq * 16 + part * 8;
      f16x8 v;
      #pragma unroll
      for (int ii = 0; ii < 8; ++ii) {
        const int k = k8 + ii;
        const int dd = dlt * 64 + k - n;
        v[ii] = ((unsigned)dd < (unsigned)TS) ? (f16)params[2047 - dd] : (f16)0.0f;
      }
      *(f16x8*)(tile + n * 128 + ((2 * k8) ^ ((n & 7) << 4))) = v;
    }
    return;
  }
  // ---- X conversion ----
  const size_t base = ((size_t)(b - 33) * 256 + tid) * 16;
  const float4 a0 = *(const float4*)&X[base];
  const float4 a1 = *(const float4*)&X[base + 4];
  const float4 a2 = *(const float4*)&X[base + 8];
  const float4 a3 = *(const float4*)&X[base + 12];
  f16x8 v0 = {(f16)a0.x, (f16)a0.y, (f16)a0.z, (f16)a0.w,
              (f16)a1.x, (f16)a1.y, (f16)a1.z, (f16)a1.w};
  f16x8 v1 = {(f16)a2.x, (f16)a2.y, (f16)a2.z, (f16)a2.w,
              (f16)a3.x, (f16)a3.y, (f16)a3.z, (f16)a3.w};
  *(f16x8*)&Xh[base] = v0;
  *(f16x8*)&Xh[base + 8] = v1;
}

// ---------------------------------------------------------------------------
// Kernel 2/3: stage A / stage C MFMA GEMMs with XCD-grouped work mapping.
// ---------------------------------------------------------------------------
__global__ __launch_bounds__(256, 2) void toep_A(
    const f16* __restrict__ Xh, const char* __restrict__ Wg,
    const float* __restrict__ biasp, f16* __restrict__ u) {
  __shared__ ToepShared lds;
  const int b = blockIdx.x;
  toep_body<true>(lds, (b & 7) * 64 + (b >> 3), Xh, Wg, biasp, (void*)u);
}

__global__ __launch_bounds__(256, 2) void toep_C(
    const f16* __restrict__ u, const char* __restrict__ WgC,
    float* __restrict__ out) {
  __shared__ ToepShared lds;
  const int b = blockIdx.x;
  toep_body<false>(lds, (b & 7) * 64 + (b >> 3), u, WgC, nullptr, (void*)out);
}

// ---------------------------------------------------------------------------
extern "C" void kernel_launch(void* const* d_in, const int* in_sizes, int n_in,
                              void* d_out, int out_size, void* d_ws, size_t ws_size,
                              hipStream_t stream) {
  const float* inputs = (const float*)d_in[0];  // [BB, TS] fp32
  const float* params = (const float*)d_in[1];  // [TS]
  const float* bias   = (const float*)d_in[2];  // [1]
  float* out = (float*)d_out;                   // [BB, TS] fp32

  char* ws = (char*)d_ws;
  f16*  Xh = (f16*)ws;                             // 16 MB
  f16*  u  = (f16*)(ws + (size_t)BB * TS * 2);     // 16 MB
  char* Wg = ws + (size_t)BB * TS * 4;             // 64 x 8 KB (A: 0..31, C: 32..63)

  conv_prep<<<2081, 256, 0, stream>>>(inputs, Xh, params, Wg);
  toep_A<<<512, 256, 0, stream>>>(Xh, Wg, bias, u);
  toep_C<<<512, 256, 0, stream>>>(u, Wg + 32 * 8192, out);
}

// Round 9
// 107.714 us; speedup vs baseline: 1.4063x; 1.4063x over previous
//
#include <hip/hip_runtime.h>
#include <hip/hip_bf16.h>

typedef _Float16 f16;
typedef _Float16 f16x8 __attribute__((ext_vector_type(8)));
typedef float f32x4 __attribute__((ext_vector_type(4)));

constexpr int TS = 2048;   // time steps / params length
constexpr int BB = 4096;   // batch rows

struct ToepShared { char Xs[16384]; char Ws[8192]; };

// h-block shared (40 KB), all accesses lane-consecutive or uniform-broadcast
struct __align__(16) HShared {
  float rq[2048];          // rq[z] = p[2047-z]
  float h[2048];           // impulse response
  float histp_store[2048]; // histp = store+1024; zero prefix absorbs r>i reads
  float part_buf[4096];    // per-(s)-partial sums, SPLIT*n <= 4096 floats
};

// ---------------------------------------------------------------------------
// toep body: triangular Toeplitz x dense GEMM via mfma_f32_16x16x32_f16.
//   REV=true  (stage A): u[b,m] = bias + sum_{k>=m} prv[k-m] * x[b,k] -> f16
//   REV=false (stage C): y[b,m] =        sum_{k<=m} h[m-k]  * u[b,k] -> f32
// Block: 128 rows x 64 cols, 4 waves (2x2), BK=64, column pairing (px,31-px).
// ---------------------------------------------------------------------------
template <bool REV>
__device__ void toep_body(ToepShared& lds, int w, const f16* __restrict__ Xg,
                          const char* __restrict__ Wg,
                          const float* __restrict__ biasp, void* __restrict__ Yg) {
  char* Xs = lds.Xs;
  char* Ws = lds.Ws;
  const int tid = threadIdx.x;
  const int lane = tid & 63;
  const int wid = tid >> 6;
  const int wrow = (wid >> 1) * 64;
  const int wcol = (wid & 1) * 32;
  const int px = w & 15;
  const int b0 = (w >> 4) * 128;

  float binit = 0.0f;
  if (REV) binit = biasp[0];

  for (int phase = 0; phase < 2; ++phase) {
    const int mblk = phase ? (31 - px) : px;
    const int m0 = mblk * 64;
    const int k0b = REV ? m0 : 0;
    const int k0e = REV ? TS : (m0 + 64);

    f32x4 acc[4][2];
    #pragma unroll
    for (int i = 0; i < 4; ++i)
      #pragma unroll
      for (int j = 0; j < 2; ++j) acc[i][j] = {binit, binit, binit, binit};

    for (int k0 = k0b; k0 < k0e; k0 += 64) {
      __syncthreads();
      // stage X tile: 16 x 1KB, inverse-swizzled per-lane global source
      #pragma unroll
      for (int t2 = 0; t2 < 4; ++t2) {
        const int t = wid * 4 + t2;
        const int row = t * 8 + (lane >> 3);
        const char* src = (const char*)Xg + ((size_t)(b0 + row) * TS + k0) * 2
                          + (((lane & 7) * 16) ^ ((row & 7) << 4));
        __builtin_amdgcn_global_load_lds(
            (const __attribute__((address_space(1))) unsigned int*)src,
            (__attribute__((address_space(3))) unsigned int*)(Xs + t * 1024),
            16, 0, 0);
      }
      // stage W tile (pre-swizzled in global): 8 x 1KB
      const int dlt = (REV ? (k0 - m0) : (m0 - k0)) >> 6;
      const char* wsrc = Wg + (size_t)dlt * 8192;
      #pragma unroll
      for (int p = 0; p < 2; ++p) {
        const int t = wid * 2 + p;
        __builtin_amdgcn_global_load_lds(
            (const __attribute__((address_space(1))) unsigned int*)(wsrc + t * 1024 + lane * 16),
            (__attribute__((address_space(3))) unsigned int*)(Ws + t * 1024),
            16, 0, 0);
      }
      __syncthreads();

      #pragma unroll
      for (int ks = 0; ks < 2; ++ks) {
        const int colb = ks * 64 + ((lane >> 4) * 16);
        f16x8 af[4], bf[2];
        #pragma unroll
        for (int i = 0; i < 4; ++i) {
          const int row = wrow + i * 16 + (lane & 15);
          af[i] = *(const f16x8*)(Xs + row * 128 + (colb ^ ((row & 7) << 4)));
        }
        #pragma unroll
        for (int j = 0; j < 2; ++j) {
          const int n = wcol + j * 16 + (lane & 15);
          bf[j] = *(const f16x8*)(Ws + n * 128 + (colb ^ ((n & 7) << 4)));
        }
        #pragma unroll
        for (int i = 0; i < 4; ++i)
          #pragma unroll
          for (int j = 0; j < 2; ++j)
            acc[i][j] = __builtin_amdgcn_mfma_f32_16x16x32_f16(
                af[i], bf[j], acc[i][j], 0, 0, 0);
      }
    }

    // epilogue: C/D layout col=lane&15, row=(lane>>4)*4+r
    #pragma unroll
    for (int i = 0; i < 4; ++i) {
      #pragma unroll
      for (int j = 0; j < 2; ++j) {
        #pragma unroll
        for (int r = 0; r < 4; ++r) {
          const int row = b0 + wrow + i * 16 + (lane >> 4) * 4 + r;
          const int col = m0 + wcol + j * 16 + (lane & 15);
          if (REV)
            ((f16*)Yg)[(size_t)row * TS + col] = (f16)acc[i][j][r];
          else
            ((float*)Yg)[(size_t)row * TS + col] = acc[i][j][r];
        }
      }
    }
  }
}

// ---------------------------------------------------------------------------
// h-block (1024 threads, 16 waves): impulse response by 6 doubling phases.
//   doubling n -> 2n:  hist[i] = sum_{m<n} h[m] p[n-1+i-m]      (i in [0,n))
//                      h[n+i]  = sum_{r<=i} h[r] hist[i-r]
// Parallelism: outputs split into NC chunks of 256 (64 lanes x 4 consecutive);
// reduction dim split into SPLIT parts; wave (c,s) computes a partial over its
// m/r part into part_buf[s*n + i]; a cheap reduce pass sums SPLIT partials.
// 16 waves = 4/SIMD -> LDS latency hidden by TLP (not compiler scheduling).
// Inner body: round-6 sliding 2-chunk window (1 lane-b128 + 1 uniform-b128 +
// 16 FMA per 4 m-terms, ~25 live regs, measured conflict-free).
// ---------------------------------------------------------------------------
__device__ void h_block_body(HShared& S, const float* __restrict__ params,
                             char* __restrict__ WgC) {
  float* rq = S.rq;
  float* h_s = S.h;
  float* histp = S.histp_store + 1024;
  const int tid = threadIdx.x;  // 0..1023
  const int lane = tid & 63;
  const int wave = tid >> 6;    // 0..15

  // rq[z] = p[2047-z]
  if (tid < 512) {
    f32x4 pv = *(const f32x4*)&params[2044 - 4 * tid];
    f32x4 v = {pv[3], pv[2], pv[1], pv[0]};
    *(f32x4*)&rq[4 * tid] = v;
  }
  // zero histp prefix [0,1024)
  if (tid < 256) {
    f32x4 z = {0.0f, 0.0f, 0.0f, 0.0f};
    *(f32x4*)&S.histp_store[4 * tid] = z;
  }
  __syncthreads();

  // bootstrap h[0..31] in wave 0: h[m] = sum_{l<m} h[l] p[m-1-l]
  if (wave == 0) {
    float hv = (lane == 0) ? 1.0f : 0.0f;
    for (int m = 1; m < 32; ++m) {
      float partial = (lane < m) ? hv * rq[2048 - m + lane] : 0.0f;
      #pragma unroll
      for (int off = 32; off; off >>= 1) partial += __shfl_xor(partial, off);
      if (lane == m) hv = partial;
    }
    if (lane < 32) h_s[lane] = hv;
  }
  __syncthreads();

  #pragma unroll 1
  for (int n = 32; n < 2048; n <<= 1) {
    int NC = n >> 8; if (NC < 1) NC = 1;         // output chunks of 256
    int SPLIT = 16 / NC;                          // reduction parts
    if (SPLIT > (n >> 2)) SPLIT = n >> 2;
    const int part = n / SPLIT;                   // multiple of 4
    const int T = part >> 2;
    const int c = wave % NC;
    const int s = wave / NC;
    const int iB = c * 256 + (lane << 2);
    const int m0 = s * part;
    const bool act = (s < SPLIT) && (iB < n);

    // ---- phase H partial: sum_{m in [m0,m0+part)} h[m] rq[2048-n-i+m] ----
    if (act) {
      float a0 = 0.0f, a1 = 0.0f, a2 = 0.0f, a3 = 0.0f;
      const float* wp = &rq[2048 - n - iB + m0];
      f32x4 prev = *(const f32x4*)(wp - 4);
      for (int t = 0; t < T; ++t) {
        const f32x4 lo = prev;
        const f32x4 hi = *(const f32x4*)(wp + 4 * t);
        const f32x4 h4 = *(const f32x4*)&h_s[m0 + 4 * t];  // uniform
        a0 += h4[0] * hi[0] + h4[1] * hi[1] + h4[2] * hi[2] + h4[3] * hi[3];
        a1 += h4[0] * lo[3] + h4[1] * hi[0] + h4[2] * hi[1] + h4[3] * hi[2];
        a2 += h4[0] * lo[2] + h4[1] * lo[3] + h4[2] * hi[0] + h4[3] * hi[1];
        a3 += h4[0] * lo[1] + h4[1] * lo[2] + h4[2] * lo[3] + h4[3] * hi[0];
        prev = hi;
      }
      f32x4 out = {a0, a1, a2, a3};
      *(f32x4*)&S.part_buf[s * n + iB] = out;
    }
    __syncthreads();
    // ---- reduce H: histp[i] = sum_s part ----
    if (tid < n) {
      float v = 0.0f;
      for (int s2 = 0; s2 < SPLIT; ++s2) v += S.part_buf[s2 * n + tid];
      histp[tid] = v;
    }
    __syncthreads();

    // ---- phase S partial: sum_{r in [m0,m0+part), r<=i} h[r] histp[i-r] ----
    if (act) {
      int wmax = c * 256 + 255; if (wmax > n - 1) wmax = n - 1;
      int T2 = ((wmax - m0) >> 2) + 1;
      if (T2 > T) T2 = T;
      if (T2 < 0) T2 = 0;
      float a0 = 0.0f, a1 = 0.0f, a2 = 0.0f, a3 = 0.0f;
      const float* hp = &histp[iB - m0];
      f32x4 hi = *(const f32x4*)hp;
      for (int t = 0; t < T2; ++t) {
        const f32x4 lo = *(const f32x4*)(hp - 4 - 4 * t);  // prefix-safe
        const f32x4 h4 = *(const f32x4*)&h_s[m0 + 4 * t];  // uniform
        a0 += h4[0] * hi[0] + h4[1] * lo[3] + h4[2] * lo[2] + h4[3] * lo[1];
        a1 += h4[0] * hi[1] + h4[1] * hi[0] + h4[2] * lo[3] + h4[3] * lo[2];
        a2 += h4[0] * hi[2] + h4[1] * hi[1] + h4[2] * hi[0] + h4[3] * lo[3];
        a3 += h4[0] * hi[3] + h4[1] * hi[2] + h4[2] * hi[1] + h4[3] * hi[0];
        hi = lo;
      }
      f32x4 out = {a0, a1, a2, a3};
      *(f32x4*)&S.part_buf[s * n + iB] = out;
    }
    __syncthreads();
    // ---- reduce S: h[n+i] = sum_s part ----
    if (tid < n) {
      float v = 0.0f;
      for (int s2 = 0; s2 < SPLIT; ++s2) v += S.part_buf[s2 * n + tid];
      h_s[n + tid] = v;
    }
    __syncthreads();
  }

  // ---- stage-C W tiles: W[k][n2] = h[dlt*64 + n2 - k], pre-swizzled ----
  const int kq = (tid >> 6) & 3;  // 0..3
  const int n2 = tid & 63;        // 0..63
  for (int dlt = tid >> 8; dlt < 32; dlt += 4) {
    char* tile = WgC + (size_t)dlt * 8192;
    #pragma unroll
    for (int part2 = 0; part2 < 2; ++part2) {
      const int k8 = kq * 16 + part2 * 8;
      f16x8 v;
      #pragma unroll
      for (int ii = 0; ii < 8; ++ii) {
        const int dd = dlt * 64 + n2 - (k8 + ii);
        v[ii] = ((unsigned)dd < (unsigned)TS) ? (f16)h_s[dd] : (f16)0.0f;
      }
      *(f16x8*)(tile + n2 * 128 + ((2 * k8) ^ ((n2 & 7) << 4))) = v;
    }
  }
}

// ---------------------------------------------------------------------------
// Kernel 1 (1024 threads): block 0 = h + stage-C W tiles; blocks 1..8 =
// stage-A W tiles (4 each); blocks 9..520 = X fp32->f16 conversion.
// ---------------------------------------------------------------------------
__global__ __launch_bounds__(1024, 1) void conv_prep(
    const float* __restrict__ X, f16* __restrict__ Xh,
    const float* __restrict__ params, char* __restrict__ Wg) {
  __shared__ HShared S;
  const int b = blockIdx.x;
  const int tid = threadIdx.x;

  if (b == 0) {  // ---- h computation + stage-C W tiles ----
    h_block_body(S, params, Wg + 32 * 8192);
    return;
  }
  if (b <= 8) {  // ---- stage-A W tiles: W[k][n] = p[2047-(dlt*64+k-n)] ----
    const int dlt = (b - 1) * 4 + (tid >> 8);
    char* tile = Wg + (size_t)dlt * 8192;
    const int s2 = tid & 255;
    const int n = s2 >> 2, kq = s2 & 3;
    #pragma unroll
    for (int part = 0; part < 2; ++part) {
      const int k8 = kq * 16 + part * 8;
      f16x8 v;
      #pragma unroll
      for (int ii = 0; ii < 8; ++ii) {
        const int k = k8 + ii;
        const int dd = dlt * 64 + k - n;
        v[ii] = ((unsigned)dd < (unsigned)TS) ? (f16)params[2047 - dd] : (f16)0.0f;
      }
      *(f16x8*)(tile + n * 128 + ((2 * k8) ^ ((n & 7) << 4))) = v;
    }
    return;
  }
  // ---- X conversion ----
  const size_t base = ((size_t)(b - 9) * 1024 + tid) * 16;
  const float4 a0 = *(const float4*)&X[base];
  const float4 a1 = *(const float4*)&X[base + 4];
  const float4 a2 = *(const float4*)&X[base + 8];
  const float4 a3 = *(const float4*)&X[base + 12];
  f16x8 v0 = {(f16)a0.x, (f16)a0.y, (f16)a0.z, (f16)a0.w,
              (f16)a1.x, (f16)a1.y, (f16)a1.z, (f16)a1.w};
  f16x8 v1 = {(f16)a2.x, (f16)a2.y, (f16)a2.z, (f16)a2.w,
              (f16)a3.x, (f16)a3.y, (f16)a3.z, (f16)a3.w};
  *(f16x8*)&Xh[base] = v0;
  *(f16x8*)&Xh[base + 8] = v1;
}

// ---------------------------------------------------------------------------
// Kernel 2/3: stage A / stage C MFMA GEMMs with XCD-grouped work mapping.
// ---------------------------------------------------------------------------
__global__ __launch_bounds__(256, 2) void toep_A(
    const f16* __restrict__ Xh, const char* __restrict__ Wg,
    const float* __restrict__ biasp, f16* __restrict__ u) {
  __shared__ ToepShared lds;
  const int b = blockIdx.x;
  toep_body<true>(lds, (b & 7) * 64 + (b >> 3), Xh, Wg, biasp, (void*)u);
}

__global__ __launch_bounds__(256, 2) void toep_C(
    const f16* __restrict__ u, const char* __restrict__ WgC,
    float* __restrict__ out) {
  __shared__ ToepShared lds;
  const int b = blockIdx.x;
  toep_body<false>(lds, (b & 7) * 64 + (b >> 3), u, WgC, nullptr, (void*)out);
}

// ---------------------------------------------------------------------------
extern "C" void kernel_launch(void* const* d_in, const int* in_sizes, int n_in,
                              void* d_out, int out_size, void* d_ws, size_t ws_size,
                              hipStream_t stream) {
  const float* inputs = (const float*)d_in[0];  // [BB, TS] fp32
  const float* params = (const float*)d_in[1];  // [TS]
  const float* bias   = (const float*)d_in[2];  // [1]
  float* out = (float*)d_out;                   // [BB, TS] fp32

  char* ws = (char*)d_ws;
  f16*  Xh = (f16*)ws;                             // 16 MB
  f16*  u  = (f16*)(ws + (size_t)BB * TS * 2);     // 16 MB
  char* Wg = ws + (size_t)BB * TS * 4;             // 64 x 8 KB (A: 0..31, C: 32..63)

  conv_prep<<<521, 1024, 0, stream>>>(inputs, Xh, params, Wg);
  toep_A<<<512, 256, 0, stream>>>(Xh, Wg, bias, u);
  toep_C<<<512, 256, 0, stream>>>(u, Wg + 32 * 8192, out);
}

// Round 10
// 95.501 us; speedup vs baseline: 1.5861x; 1.1279x over previous
//
#include <hip/hip_runtime.h>
#include <hip/hip_bf16.h>

typedef _Float16 f16;
typedef _Float16 f16x8 __attribute__((ext_vector_type(8)));
typedef float f32x4 __attribute__((ext_vector_type(4)));

constexpr int TS = 2048;   // time steps / params length
constexpr int BB = 4096;   // batch rows

struct ToepShared { char Xs[16384]; char Ws[8192]; };

// h-block shared (40 KB)
struct __align__(16) HShared {
  float rq[2048];          // rq[z] = p[2047-z]
  float h[2048];           // impulse response (only [0,1024) filled here)
  float histp_store[2048]; // histp = store+1024; zero prefix absorbs r>i reads
  float part_buf[4096];    // per-split partials
};

// ---------------------------------------------------------------------------
// toep body: triangular Toeplitz x dense GEMM via mfma_f32_16x16x32_f16.
//   REV=true  (stage A): u[b,m] = bias + sum_{k>=m} prv[k-m] * x[b,k] -> f16
//   REV=false (stage C): y[b,m] =        sum_{k<=m} h[m-k]  * u[b,k] -> f32
// Block: 128 rows x 64 cols, 4 waves (2x2), BK=64, column pairing (px,31-px).
// ---------------------------------------------------------------------------
template <bool REV>
__device__ void toep_body(ToepShared& lds, int w, const f16* __restrict__ Xg,
                          const char* __restrict__ Wg,
                          const float* __restrict__ biasp, void* __restrict__ Yg) {
  char* Xs = lds.Xs;
  char* Ws = lds.Ws;
  const int tid = threadIdx.x;
  const int lane = tid & 63;
  const int wid = tid >> 6;
  const int wrow = (wid >> 1) * 64;
  const int wcol = (wid & 1) * 32;
  const int px = w & 15;
  const int b0 = (w >> 4) * 128;

  float binit = 0.0f;
  if (REV) binit = biasp[0];

  for (int phase = 0; phase < 2; ++phase) {
    const int mblk = phase ? (31 - px) : px;
    const int m0 = mblk * 64;
    const int k0b = REV ? m0 : 0;
    const int k0e = REV ? TS : (m0 + 64);

    f32x4 acc[4][2];
    #pragma unroll
    for (int i = 0; i < 4; ++i)
      #pragma unroll
      for (int j = 0; j < 2; ++j) acc[i][j] = {binit, binit, binit, binit};

    for (int k0 = k0b; k0 < k0e; k0 += 64) {
      __syncthreads();
      // stage X tile: 16 x 1KB, inverse-swizzled per-lane global source
      #pragma unroll
      for (int t2 = 0; t2 < 4; ++t2) {
        const int t = wid * 4 + t2;
        const int row = t * 8 + (lane >> 3);
        const char* src = (const char*)Xg + ((size_t)(b0 + row) * TS + k0) * 2
                          + (((lane & 7) * 16) ^ ((row & 7) << 4));
        __builtin_amdgcn_global_load_lds(
            (const __attribute__((address_space(1))) unsigned int*)src,
            (__attribute__((address_space(3))) unsigned int*)(Xs + t * 1024),
            16, 0, 0);
      }
      // stage W tile (pre-swizzled in global): 8 x 1KB
      const int dlt = (REV ? (k0 - m0) : (m0 - k0)) >> 6;
      const char* wsrc = Wg + (size_t)dlt * 8192;
      #pragma unroll
      for (int p = 0; p < 2; ++p) {
        const int t = wid * 2 + p;
        __builtin_amdgcn_global_load_lds(
            (const __attribute__((address_space(1))) unsigned int*)(wsrc + t * 1024 + lane * 16),
            (__attribute__((address_space(3))) unsigned int*)(Ws + t * 1024),
            16, 0, 0);
      }
      __syncthreads();

      #pragma unroll
      for (int ks = 0; ks < 2; ++ks) {
        const int colb = ks * 64 + ((lane >> 4) * 16);
        f16x8 af[4], bf[2];
        #pragma unroll
        for (int i = 0; i < 4; ++i) {
          const int row = wrow + i * 16 + (lane & 15);
          af[i] = *(const f16x8*)(Xs + row * 128 + (colb ^ ((row & 7) << 4)));
        }
        #pragma unroll
        for (int j = 0; j < 2; ++j) {
          const int n = wcol + j * 16 + (lane & 15);
          bf[j] = *(const f16x8*)(Ws + n * 128 + (colb ^ ((n & 7) << 4)));
        }
        #pragma unroll
        for (int i = 0; i < 4; ++i)
          #pragma unroll
          for (int j = 0; j < 2; ++j)
            acc[i][j] = __builtin_amdgcn_mfma_f32_16x16x32_f16(
                af[i], bf[j], acc[i][j], 0, 0, 0);
      }
    }

    // epilogue: C/D layout col=lane&15, row=(lane>>4)*4+r
    #pragma unroll
    for (int i = 0; i < 4; ++i) {
      #pragma unroll
      for (int j = 0; j < 2; ++j) {
        #pragma unroll
        for (int r = 0; r < 4; ++r) {
          const int row = b0 + wrow + i * 16 + (lane >> 4) * 4 + r;
          const int col = m0 + wcol + j * 16 + (lane & 15);
          if (REV)
            ((f16*)Yg)[(size_t)row * TS + col] = (f16)acc[i][j][r];
          else
            ((float*)Yg)[(size_t)row * TS + col] = acc[i][j][r];
        }
      }
    }
  }
}

// ---------------------------------------------------------------------------
// h-small (1024 threads, 16 waves): bootstrap + doubling phases n=32..512,
// producing h[0..1024) which is written to global h_g. (round-9 body, loop
// bound reduced; W_C build moved out.)
// ---------------------------------------------------------------------------
__device__ void h_block_body(HShared& S, const float* __restrict__ params,
                             float* __restrict__ h_g) {
  float* rq = S.rq;
  float* h_s = S.h;
  float* histp = S.histp_store + 1024;
  const int tid = threadIdx.x;  // 0..1023
  const int lane = tid & 63;
  const int wave = tid >> 6;    // 0..15

  if (tid < 512) {
    f32x4 pv = *(const f32x4*)&params[2044 - 4 * tid];
    f32x4 v = {pv[3], pv[2], pv[1], pv[0]};
    *(f32x4*)&rq[4 * tid] = v;
  }
  if (tid < 256) {
    f32x4 z = {0.0f, 0.0f, 0.0f, 0.0f};
    *(f32x4*)&S.histp_store[4 * tid] = z;
  }
  __syncthreads();

  // bootstrap h[0..31] in wave 0
  if (wave == 0) {
    float hv = (lane == 0) ? 1.0f : 0.0f;
    for (int m = 1; m < 32; ++m) {
      float partial = (lane < m) ? hv * rq[2048 - m + lane] : 0.0f;
      #pragma unroll
      for (int off = 32; off; off >>= 1) partial += __shfl_xor(partial, off);
      if (lane == m) hv = partial;
    }
    if (lane < 32) h_s[lane] = hv;
  }
  __syncthreads();

  #pragma unroll 1
  for (int n = 32; n < 1024; n <<= 1) {
    int NC = n >> 8; if (NC < 1) NC = 1;
    int SPLIT = 16 / NC;
    if (SPLIT > (n >> 2)) SPLIT = n >> 2;
    const int part = n / SPLIT;
    const int T = part >> 2;
    const int c = wave % NC;
    const int s = wave / NC;
    const int iB = c * 256 + (lane << 2);
    const int m0 = s * part;
    const bool act = (s < SPLIT) && (iB < n);

    if (act) {
      float a0 = 0.0f, a1 = 0.0f, a2 = 0.0f, a3 = 0.0f;
      const float* wp = &rq[2048 - n - iB + m0];
      f32x4 prev = *(const f32x4*)(wp - 4);
      for (int t = 0; t < T; ++t) {
        const f32x4 lo = prev;
        const f32x4 hi = *(const f32x4*)(wp + 4 * t);
        const f32x4 h4 = *(const f32x4*)&h_s[m0 + 4 * t];
        a0 += h4[0] * hi[0] + h4[1] * hi[1] + h4[2] * hi[2] + h4[3] * hi[3];
        a1 += h4[0] * lo[3] + h4[1] * hi[0] + h4[2] * hi[1] + h4[3] * hi[2];
        a2 += h4[0] * lo[2] + h4[1] * lo[3] + h4[2] * hi[0] + h4[3] * hi[1];
        a3 += h4[0] * lo[1] + h4[1] * lo[2] + h4[2] * lo[3] + h4[3] * hi[0];
        prev = hi;
      }
      f32x4 out = {a0, a1, a2, a3};
      *(f32x4*)&S.part_buf[s * n + iB] = out;
    }
    __syncthreads();
    if (tid < n) {
      float v = 0.0f;
      for (int s2 = 0; s2 < SPLIT; ++s2) v += S.part_buf[s2 * n + tid];
      histp[tid] = v;
    }
    __syncthreads();

    if (act) {
      int wmax = c * 256 + 255; if (wmax > n - 1) wmax = n - 1;
      int T2 = ((wmax - m0) >> 2) + 1;
      if (T2 > T) T2 = T;
      if (T2 < 0) T2 = 0;
      float a0 = 0.0f, a1 = 0.0f, a2 = 0.0f, a3 = 0.0f;
      const float* hp = &histp[iB - m0];
      f32x4 hi = *(const f32x4*)hp;
      for (int t = 0; t < T2; ++t) {
        const f32x4 lo = *(const f32x4*)(hp - 4 - 4 * t);
        const f32x4 h4 = *(const f32x4*)&h_s[m0 + 4 * t];
        a0 += h4[0] * hi[0] + h4[1] * lo[3] + h4[2] * lo[2] + h4[3] * lo[1];
        a1 += h4[0] * hi[1] + h4[1] * hi[0] + h4[2] * lo[3] + h4[3] * lo[2];
        a2 += h4[0] * hi[2] + h4[1] * hi[1] + h4[2] * hi[0] + h4[3] * lo[3];
        a3 += h4[0] * hi[3] + h4[1] * hi[2] + h4[2] * hi[1] + h4[3] * hi[0];
        hi = lo;
      }
      f32x4 out = {a0, a1, a2, a3};
      *(f32x4*)&S.part_buf[s * n + iB] = out;
    }
    __syncthreads();
    if (tid < n) {
      float v = 0.0f;
      for (int s2 = 0; s2 < SPLIT; ++s2) v += S.part_buf[s2 * n + tid];
      h_s[n + tid] = v;
    }
    __syncthreads();
  }

  // write h[0..1024) to global
  if (tid < 256) *(f32x4*)&h_g[4 * tid] = *(const f32x4*)&h_s[4 * tid];
}

// ---------------------------------------------------------------------------
// Grid-parallel final doubling phase (n=1024), exact f32 math.
//   H: hist[i] = sum_{m<1024} h[m] rq[1024 - i + m],  i in [0,1024)
//   S: h[1024+i] = sum_{r<=i} h[r] hist[i-r]
// 4 blocks x 256 thr each; block B owns outputs [256B, 256B+256); reduction
// split across 4 waves; LDS-staged operands; partials reduced in LDS.
// ---------------------------------------------------------------------------
__global__ __launch_bounds__(256, 1) void h_H1024(
    const float* __restrict__ params, const float* __restrict__ h_g,
    float* __restrict__ hist_g) {
  __shared__ __align__(16) float rq[2048];
  __shared__ __align__(16) float hl[1024];
  __shared__ __align__(16) float part[1024];
  const int tid = threadIdx.x;
  const int lane = tid & 63;
  const int wave = tid >> 6;
  const int B = blockIdx.x;

  for (int c = tid; c < 512; c += 256) {
    f32x4 pv = *(const f32x4*)&params[2044 - 4 * c];
    f32x4 v = {pv[3], pv[2], pv[1], pv[0]};
    *(f32x4*)&rq[4 * c] = v;
  }
  *(f32x4*)&hl[4 * tid] = *(const f32x4*)&h_g[4 * tid];
  __syncthreads();

  const int iB = B * 256 + (lane << 2);
  const int m0 = wave * 256;
  float a0 = 0.0f, a1 = 0.0f, a2 = 0.0f, a3 = 0.0f;
  const float* wp = &rq[1024 - iB + m0];
  f32x4 prev = *(const f32x4*)(wp - 4);
  #pragma unroll 4
  for (int t = 0; t < 64; ++t) {
    const f32x4 lo = prev;
    const f32x4 hi = *(const f32x4*)(wp + 4 * t);
    const f32x4 h4 = *(const f32x4*)&hl[m0 + 4 * t];
    a0 += h4[0] * hi[0] + h4[1] * hi[1] + h4[2] * hi[2] + h4[3] * hi[3];
    a1 += h4[0] * lo[3] + h4[1] * hi[0] + h4[2] * hi[1] + h4[3] * hi[2];
    a2 += h4[0] * lo[2] + h4[1] * lo[3] + h4[2] * hi[0] + h4[3] * hi[1];
    a3 += h4[0] * lo[1] + h4[1] * lo[2] + h4[2] * lo[3] + h4[3] * hi[0];
    prev = hi;
  }
  f32x4 out = {a0, a1, a2, a3};
  *(f32x4*)&part[wave * 256 + (lane << 2)] = out;
  __syncthreads();
  const float v = (part[tid] + part[256 + tid]) + (part[512 + tid] + part[768 + tid]);
  hist_g[B * 256 + tid] = v;
}

__global__ __launch_bounds__(256, 1) void h_S1024(
    const float* __restrict__ hist_g, float* __restrict__ h_g) {
  __shared__ __align__(16) float hps[2048];  // histp = hps+1024, zero prefix
  __shared__ __align__(16) float hl[1024];
  __shared__ __align__(16) float part[1024];
  const int tid = threadIdx.x;
  const int lane = tid & 63;
  const int wave = tid >> 6;
  const int B = blockIdx.x;

  {
    f32x4 z = {0.0f, 0.0f, 0.0f, 0.0f};
    *(f32x4*)&hps[4 * tid] = z;
    *(f32x4*)&hps[1024 + 4 * tid] = *(const f32x4*)&hist_g[4 * tid];
    *(f32x4*)&hl[4 * tid] = *(const f32x4*)&h_g[4 * tid];
  }
  __syncthreads();

  float* histp = hps + 1024;
  const int iB = B * 256 + (lane << 2);
  const int m0 = wave * 256;
  const int wmax = B * 256 + 255;
  int T2 = 0;
  if (wmax >= m0) { T2 = ((wmax - m0) >> 2) + 1; if (T2 > 64) T2 = 64; }

  float a0 = 0.0f, a1 = 0.0f, a2 = 0.0f, a3 = 0.0f;
  const float* hp = &histp[iB - m0];
  f32x4 hi = *(const f32x4*)hp;
  #pragma unroll 4
  for (int t = 0; t < T2; ++t) {
    const f32x4 lo = *(const f32x4*)(hp - 4 - 4 * t);
    const f32x4 h4 = *(const f32x4*)&hl[m0 + 4 * t];
    a0 += h4[0] * hi[0] + h4[1] * lo[3] + h4[2] * lo[2] + h4[3] * lo[1];
    a1 += h4[0] * hi[1] + h4[1] * hi[0] + h4[2] * lo[3] + h4[3] * lo[2];
    a2 += h4[0] * hi[2] + h4[1] * hi[1] + h4[2] * hi[0] + h4[3] * lo[3];
    a3 += h4[0] * hi[3] + h4[1] * hi[2] + h4[2] * hi[1] + h4[3] * hi[0];
    hi = lo;
  }
  f32x4 out = {a0, a1, a2, a3};
  *(f32x4*)&part[wave * 256 + (lane << 2)] = out;
  __syncthreads();
  const float v = (part[tid] + part[256 + tid]) + (part[512 + tid] + part[768 + tid]);
  h_g[1024 + B * 256 + tid] = v;
}

// ---------------------------------------------------------------------------
// Kernel 1 (1024 threads): block 0 = h-small (-> h_g[0..1024)); blocks 1..8 =
// stage-A W tiles (4 each); blocks 9..520 = X fp32->f16 conversion.
// ---------------------------------------------------------------------------
__global__ __launch_bounds__(1024, 1) void conv_prep(
    const float* __restrict__ X, f16* __restrict__ Xh,
    const float* __restrict__ params, char* __restrict__ Wg,
    float* __restrict__ h_g) {
  __shared__ HShared S;
  const int b = blockIdx.x;
  const int tid = threadIdx.x;

  if (b == 0) {
    h_block_body(S, params, h_g);
    return;
  }
  if (b <= 8) {  // stage-A W tiles: W[k][n] = p[2047-(dlt*64+k-n)]
    const int dlt = (b - 1) * 4 + (tid >> 8);
    char* tile = Wg + (size_t)dlt * 8192;
    const int s2 = tid & 255;
    const int n = s2 >> 2, kq = s2 & 3;
    #pragma unroll
    for (int part = 0; part < 2; ++part) {
      const int k8 = kq * 16 + part * 8;
      f16x8 v;
      #pragma unroll
      for (int ii = 0; ii < 8; ++ii) {
        const int k = k8 + ii;
        const int dd = dlt * 64 + k - n;
        v[ii] = ((unsigned)dd < (unsigned)TS) ? (f16)params[2047 - dd] : (f16)0.0f;
      }
      *(f16x8*)(tile + n * 128 + ((2 * k8) ^ ((n & 7) << 4))) = v;
    }
    return;
  }
  // X conversion
  const size_t base = ((size_t)(b - 9) * 1024 + tid) * 16;
  const float4 a0 = *(const float4*)&X[base];
  const float4 a1 = *(const float4*)&X[base + 4];
  const float4 a2 = *(const float4*)&X[base + 8];
  const float4 a3 = *(const float4*)&X[base + 12];
  f16x8 v0 = {(f16)a0.x, (f16)a0.y, (f16)a0.z, (f16)a0.w,
              (f16)a1.x, (f16)a1.y, (f16)a1.z, (f16)a1.w};
  f16x8 v1 = {(f16)a2.x, (f16)a2.y, (f16)a2.z, (f16)a2.w,
              (f16)a3.x, (f16)a3.y, (f16)a3.z, (f16)a3.w};
  *(f16x8*)&Xh[base] = v0;
  *(f16x8*)&Xh[base + 8] = v1;
}

// ---------------------------------------------------------------------------
// Kernel: stage A GEMM (blocks 0..511) + stage-C W-tile build (blocks
// 512..515, 8 dlt each, reading full h from global — overlaps the GEMM).
// ---------------------------------------------------------------------------
__global__ __launch_bounds__(256, 2) void toep_A(
    const f16* __restrict__ Xh, const char* __restrict__ Wg,
    const float* __restrict__ biasp, f16* __restrict__ u,
    const float* __restrict__ h_g, char* __restrict__ WgC) {
  __shared__ ToepShared lds;
  const int b = blockIdx.x;
  if (b >= 512) {
    const int bw = b - 512;
    const int tid = threadIdx.x;
    const int kq = tid >> 6;
    const int n2 = tid & 63;
    for (int dlt = bw * 8; dlt < bw * 8 + 8; ++dlt) {
      char* tile = WgC + (size_t)dlt * 8192;
      #pragma unroll
      for (int part = 0; part < 2; ++part) {
        const int k8 = kq * 16 + part * 8;
        f16x8 v;
        #pragma unroll
        for (int ii = 0; ii < 8; ++ii) {
          const int dd = dlt * 64 + n2 - (k8 + ii);
          v[ii] = ((unsigned)dd < (unsigned)TS) ? (f16)h_g[dd] : (f16)0.0f;
        }
        *(f16x8*)(tile + n2 * 128 + ((2 * k8) ^ ((n2 & 7) << 4))) = v;
      }
    }
    return;
  }
  toep_body<true>(lds, (b & 7) * 64 + (b >> 3), Xh, Wg, biasp, (void*)u);
}

__global__ __launch_bounds__(256, 2) void toep_C(
    const f16* __restrict__ u, const char* __restrict__ WgC,
    float* __restrict__ out) {
  __shared__ ToepShared lds;
  const int b = blockIdx.x;
  toep_body<false>(lds, (b & 7) * 64 + (b >> 3), u, WgC, nullptr, (void*)out);
}

// ---------------------------------------------------------------------------
extern "C" void kernel_launch(void* const* d_in, const int* in_sizes, int n_in,
                              void* d_out, int out_size, void* d_ws, size_t ws_size,
                              hipStream_t stream) {
  const float* inputs = (const float*)d_in[0];  // [BB, TS] fp32
  const float* params = (const float*)d_in[1];  // [TS]
  const float* bias   = (const float*)d_in[2];  // [1]
  float* out = (float*)d_out;                   // [BB, TS] fp32

  char* ws = (char*)d_ws;
  f16*   Xh    = (f16*)ws;                            // 16 MB
  f16*   u     = (f16*)(ws + (size_t)BB * TS * 2);    // 16 MB
  char*  Wg    = ws + (size_t)BB * TS * 4;            // 64 x 8 KB (A:0..31, C:32..63)
  float* h_g   = (float*)(Wg + 64 * 8192);            // 2048 floats
  float* hist_g = h_g + 2048;                         // 1024 floats

  conv_prep<<<521, 1024, 0, stream>>>(inputs, Xh, params, Wg, h_g);
  h_H1024<<<4, 256, 0, stream>>>(params, h_g, hist_g);
  h_S1024<<<4, 256, 0, stream>>>(hist_g, h_g);
  toep_A<<<516, 256, 0, stream>>>(Xh, Wg, bias, u, h_g, Wg + 32 * 8192);
  toep_C<<<512, 256, 0, stream>>>(u, Wg + 32 * 8192, out);
}